// Round 14
// baseline (564.537 us; speedup 1.0000x reference)
//
#include <hip/hip_runtime.h>
#include <hip/hip_bf16.h>

// ---------------------------------------------------------------------------
// InductiveBundleMapLearner: 2x SAGEConv (mean) -> linear -> Cayley map
// R7/R13-proven core. This round: 3-blocks/CU GEMM occupancy (512,6),
// BN-templated GEMM (GEMM2 at BN=128 -> 782 blocks), hist fused into GEMM1
// dispatch, params+cayley fused via LDS.
// ---------------------------------------------------------------------------

#define WS_ALIGN(x) (((x) + 255) & ~size_t(255))

typedef __attribute__((ext_vector_type(8))) short short8;
typedef __attribute__((ext_vector_type(4))) float floatx4;

static __device__ __forceinline__ ushort f2b(float f) {
    unsigned u = __builtin_bit_cast(unsigned, f);
    u = (u + 0x7fffu + ((u >> 16) & 1u)) >> 16;   // RNE, finite inputs
    return (ushort)u;
}
static __device__ __forceinline__ float b2f(ushort h) {
    unsigned u = ((unsigned)h) << 16;
    return __builtin_bit_cast(float, u);
}
static __device__ __forceinline__ unsigned pk2(float a, float b) {
    return (unsigned)f2b(a) | ((unsigned)f2b(b) << 16);
}

// ---------------- prep: build_wcat only (hist moved into GEMM1) ----------------

__global__ __launch_bounds__(256)
void prep_kernel(const float* __restrict__ W1l, const float* __restrict__ W1r,
                 const float* __restrict__ W2l, const float* __restrict__ W2r,
                 ushort* __restrict__ Wc1, ushort* __restrict__ Wc2) {
    int idx = blockIdx.x * blockDim.x + threadIdx.x;
    const int n1 = (512 * 512) / 8;
    const int n2 = (256 * 256) / 8;
    const float* src;
    ushort* dstp;
    if (idx < n1) {
        int e = idx * 8;
        int row = e >> 9, col = e & 511;
        src = (row < 256) ? &W1l[row * 512 + col] : &W1r[(row - 256) * 512 + col];
        dstp = &Wc1[e];
    } else if (idx < n1 + n2) {
        int e = (idx - n1) * 8;
        int row = e >> 8, col = e & 255;
        src = (row < 128) ? &W2l[row * 256 + col] : &W2r[(row - 128) * 256 + col];
        dstp = &Wc2[e];
    } else {
        return;
    }
    const float4* s4 = reinterpret_cast<const float4*>(src);
    float4 v0 = s4[0], v1 = s4[1];
    short8 o;
    o[0] = (short)f2b(v0.x); o[1] = (short)f2b(v0.y);
    o[2] = (short)f2b(v0.z); o[3] = (short)f2b(v0.w);
    o[4] = (short)f2b(v1.x); o[5] = (short)f2b(v1.y);
    o[6] = (short)f2b(v1.z); o[7] = (short)f2b(v1.w);
    *reinterpret_cast<short8*>(dstp) = o;
}

// ---------------- scan (3-phase) ----------------

__global__ __launch_bounds__(256)
void scan_phase1(const int* __restrict__ deg, int* __restrict__ bsum, int n) {
    __shared__ int red[256];
    const int t = threadIdx.x;
    const int i = blockIdx.x * 1024 + t * 4;
    int s = 0;
    if (i + 4 <= n) {
        int4 v = *reinterpret_cast<const int4*>(&deg[i]);
        s = v.x + v.y + v.z + v.w;
    } else {
        for (int k = i; k < n; ++k) s += deg[k];
    }
    red[t] = s;
    __syncthreads();
#pragma unroll
    for (int off = 128; off > 0; off >>= 1) {
        if (t < off) red[t] += red[t + off];
        __syncthreads();
    }
    if (t == 0) bsum[blockIdx.x] = red[0];
}

__global__ __launch_bounds__(256)
void scan_phase2(int* __restrict__ bsum, int* __restrict__ rowptr, int nb, int n) {
    __shared__ int sh[256];
    const int t = threadIdx.x;
    int orig = (t < nb) ? bsum[t] : 0;
    sh[t] = orig;
    __syncthreads();
#pragma unroll
    for (int off = 1; off < 256; off <<= 1) {
        int v = (t >= off) ? sh[t - off] : 0;
        __syncthreads();
        sh[t] += v;
        __syncthreads();
    }
    if (t < nb) bsum[t] = sh[t] - orig;          // exclusive block offsets
    if (t == 255) rowptr[n] = sh[255];           // total
}

// phase 3 also zero-fills cursor
__global__ __launch_bounds__(256)
void scan_phase3(const int* __restrict__ deg, const int* __restrict__ bsum,
                 int* __restrict__ rowptr, int* __restrict__ cursor, int n) {
    __shared__ int red[256];
    const int t = threadIdx.x;
    const int i = blockIdx.x * 1024 + t * 4;
    int v0 = 0, v1 = 0, v2 = 0, v3 = 0;
    if (i + 4 <= n) {
        int4 v = *reinterpret_cast<const int4*>(&deg[i]);
        v0 = v.x; v1 = v.y; v2 = v.z; v3 = v.w;
    } else {
        if (i     < n) v0 = deg[i];
        if (i + 1 < n) v1 = deg[i + 1];
        if (i + 2 < n) v2 = deg[i + 2];
        if (i + 3 < n) v3 = deg[i + 3];
    }
    int s = v0 + v1 + v2 + v3;
    red[t] = s;
    __syncthreads();
#pragma unroll
    for (int off = 1; off < 256; off <<= 1) {
        int u = (t >= off) ? red[t - off] : 0;
        __syncthreads();
        red[t] += u;
        __syncthreads();
    }
    int pre = bsum[blockIdx.x] + red[t] - s;
    if (i + 4 <= n) {
        int4 o;
        o.x = pre; o.y = pre + v0; o.z = pre + v0 + v1; o.w = pre + v0 + v1 + v2;
        *reinterpret_cast<int4*>(&rowptr[i]) = o;
        *reinterpret_cast<int4*>(&cursor[i]) = make_int4(0, 0, 0, 0);
    } else {
        if (i     < n) { rowptr[i]     = pre;                cursor[i]     = 0; }
        if (i + 1 < n) { rowptr[i + 1] = pre + v0;           cursor[i + 1] = 0; }
        if (i + 2 < n) { rowptr[i + 2] = pre + v0 + v1;      cursor[i + 2] = 0; }
        if (i + 3 < n) { rowptr[i + 3] = pre + v0 + v1 + v2; cursor[i + 3] = 0; }
    }
}

__global__ void scatter_kernel(const int* __restrict__ src, const int* __restrict__ dst,
                               const int* __restrict__ rowptr, int* __restrict__ cursor,
                               int* __restrict__ adj, int E) {
    int e = blockIdx.x * blockDim.x + threadIdx.x;
    if (e < E) {
        int d = dst[e];
        int p = atomicAdd(&cursor[d], 1);
        adj[rowptr[d] + p] = src[e];
    }
}

// ---------------- bf16 MFMA GEMM: [Cl|Cr] = A @ B^T ----------------
// 128xBN tile, BK=64, 512 threads = 8 waves (2M x 4N; each 64 x BN/4).
// B staged via global_load_lds (pre-swizzled src, linear dest).
// A: CASTA ? pipelined fp32 reg-load -> bf16 pack -> swizzled ds_write
//          : global_load_lds like B.
// HIST: blocks with blockIdx.y >= gmy do the degree histogram instead
// (independent work overlapped into this dispatch).
// LDS granule (r, g) lives at byte r*128 + ((g*16) ^ ((r&7)<<4)).

template <bool CASTA, int BN, bool HIST>
__global__ __launch_bounds__(512, 6)
void gemm_wide(const float* __restrict__ Af, const ushort* __restrict__ Ab,
               const ushort* __restrict__ B,
               ushort* __restrict__ Cl, ushort* __restrict__ Cr,
               int M, int K, int S, int gmy,
               const int* __restrict__ hdst, int* __restrict__ hdeg, int hE) {
    if (HIST) {
        if (blockIdx.y >= gmy) {
            int e = ((blockIdx.y - gmy) * gridDim.x + blockIdx.x) * 512 + threadIdx.x;
            if (e < hE) atomicAdd(&hdeg[hdst[e]], 1);
            return;
        }
    }
    constexpr int WN = BN / 4;     // cols per wave
    constexpr int NI = BN / 64;    // 16-col groups per wave (acc N dim)
    __shared__ ushort As[128 * 64];    // 16 KB
    __shared__ ushort Bs[BN * 64];     // BN/8 KB
    const int tid  = threadIdx.x;
    const int wave = tid >> 6;
    const int lane = tid & 63;
    const int row0 = blockIdx.y * 128;
    const int col0 = blockIdx.x * BN;
    const int wm = (wave & 1) * 64;
    const int wn = (wave >> 1) * WN;

    floatx4 acc[4][NI];
#pragma unroll
    for (int i = 0; i < 4; ++i)
#pragma unroll
        for (int j = 0; j < NI; ++j)
            acc[i][j] = (floatx4){0.f, 0.f, 0.f, 0.f};

    const int rsub = lane >> 3;                        // row within 8-row chunk
    const int ksw  = ((lane & 7) * 16) ^ (rsub << 4);  // pre-swizzled byte-in-row

    // CASTA addressing: thread owns row r = tid>>2, quarter qt = tid&3
    const int ar = tid >> 2;
    const int aq = tid & 3;
    int agrow = row0 + ar; if (agrow >= M) agrow = M - 1;
    const float* arow_base = CASTA ? (Af + (size_t)agrow * K + aq * 16) : nullptr;
    char* alds = (char*)As + ar * 128;
    const int arx = (ar & 7) << 4;

    float4 va0, va1, va2, va3;
    if constexpr (CASTA) {
        const float* s0 = arow_base;                   // k0 = 0 prologue
        va0 = *reinterpret_cast<const float4*>(s0 + 0);
        va1 = *reinterpret_cast<const float4*>(s0 + 4);
        va2 = *reinterpret_cast<const float4*>(s0 + 8);
        va3 = *reinterpret_cast<const float4*>(s0 + 12);
    }

    for (int k0 = 0; k0 < K; k0 += 64) {
        // ---- issue B DMA first (longest queue): BN/8 chunks, NI per wave ----
#pragma unroll
        for (int i = 0; i < NI; ++i) {
            int chunk = wave * NI + i;
            int r = chunk * 8 + rsub;
            int gcol = col0 + r;
            const char* src = (const char*)(B + (size_t)gcol * K + k0) + ksw;
            __builtin_amdgcn_global_load_lds(
                (const __attribute__((address_space(1))) unsigned int*)src,
                (__attribute__((address_space(3))) unsigned int*)(&Bs[chunk * 512]),
                16, 0, 0);
        }
        // ---- stage A ----
        if constexpr (CASTA) {
            uint4 o0 = make_uint4(pk2(va0.x, va0.y), pk2(va0.z, va0.w),
                                  pk2(va1.x, va1.y), pk2(va1.z, va1.w));
            uint4 o1 = make_uint4(pk2(va2.x, va2.y), pk2(va2.z, va2.w),
                                  pk2(va3.x, va3.y), pk2(va3.z, va3.w));
            int g0 = aq * 2;
            *reinterpret_cast<uint4*>(alds + ((g0 * 16) ^ arx))       = o0;
            *reinterpret_cast<uint4*>(alds + (((g0 + 1) * 16) ^ arx)) = o1;
            if (k0 + 64 < K) {
                const float* s1 = arow_base + k0 + 64;
                va0 = *reinterpret_cast<const float4*>(s1 + 0);
                va1 = *reinterpret_cast<const float4*>(s1 + 4);
                va2 = *reinterpret_cast<const float4*>(s1 + 8);
                va3 = *reinterpret_cast<const float4*>(s1 + 12);
            }
        } else {
            // 16 chunks, 2 per wave
#pragma unroll
            for (int i = 0; i < 2; ++i) {
                int chunk = wave * 2 + i;
                int r = chunk * 8 + rsub;
                int grow = row0 + r;
                if (grow >= M) grow = M - 1;           // clamp (stores guarded)
                const char* src = (const char*)(Ab + (size_t)grow * K + k0) + ksw;
                __builtin_amdgcn_global_load_lds(
                    (const __attribute__((address_space(1))) unsigned int*)src,
                    (__attribute__((address_space(3))) unsigned int*)(&As[chunk * 512]),
                    16, 0, 0);
            }
        }
        __syncthreads();

#pragma unroll
        for (int kk = 0; kk < 2; ++kk) {
            short8 af[4], bf[NI];
            const int kb = (kk * 64 + ((lane >> 4) << 4)) ^ ((lane & 7) << 4);
#pragma unroll
            for (int im = 0; im < 4; ++im) {
                int r = wm + im * 16 + (lane & 15);
                af[im] = *reinterpret_cast<const short8*>((const char*)As + r * 128 + kb);
            }
#pragma unroll
            for (int in = 0; in < NI; ++in) {
                int r = wn + in * 16 + (lane & 15);
                bf[in] = *reinterpret_cast<const short8*>((const char*)Bs + r * 128 + kb);
            }
#pragma unroll
            for (int im = 0; im < 4; ++im)
#pragma unroll
                for (int in = 0; in < NI; ++in)
                    acc[im][in] = __builtin_amdgcn_mfma_f32_16x16x32_bf16(
                        af[im], bf[in], acc[im][in], 0, 0, 0);
        }
        __syncthreads();
    }

    // epilogue: C/D layout col=lane&15, row=(lane>>4)*4+reg
#pragma unroll
    for (int im = 0; im < 4; ++im) {
#pragma unroll
        for (int reg = 0; reg < 4; ++reg) {
            int r = row0 + wm + im * 16 + ((lane >> 4) << 2) + reg;
            if (r < M) {
#pragma unroll
                for (int in = 0; in < NI; ++in) {
                    int g = col0 + wn + in * 16 + (lane & 15);
                    if (g < S) Cl[(size_t)r * S + g] = f2b(acc[im][in][reg]);
                    else       Cr[(size_t)r * S + (g - S)] = f2b(acc[im][in][reg]);
                }
            }
        }
    }
}

// ---------------- aggregation: h = relu(mean_l + self_r + b), bf16 ----------------
// Yl/Yr = [N, F] split buffers. LPN lanes/node, 8 ch/lane (16B short8 loads).

template <int LPN>
__global__ __launch_bounds__(256)
void aggregate_bf16(const ushort* __restrict__ Yl, const ushort* __restrict__ Yr,
                    const float* __restrict__ bias,
                    const int* __restrict__ rowptr, const int* __restrict__ adj,
                    ushort* __restrict__ H, int n) {
    constexpr int F = LPN * 8;
    const int grp = threadIdx.x / LPN;
    const int sub = threadIdx.x % LPN;
    const int node = blockIdx.x * (256 / LPN) + grp;
    if (node >= n) return;
    const int c = sub * 8;
    const int start = rowptr[node], end = rowptr[node + 1];

    float acc[8];
#pragma unroll
    for (int v = 0; v < 8; ++v) acc[v] = 0.f;

    int e = start;
    for (; e + 4 <= end; e += 4) {
        int s0 = adj[e + 0], s1 = adj[e + 1], s2 = adj[e + 2], s3 = adj[e + 3];
        short8 r0 = *reinterpret_cast<const short8*>(&Yl[(size_t)s0 * F + c]);
        short8 r1 = *reinterpret_cast<const short8*>(&Yl[(size_t)s1 * F + c]);
        short8 r2 = *reinterpret_cast<const short8*>(&Yl[(size_t)s2 * F + c]);
        short8 r3 = *reinterpret_cast<const short8*>(&Yl[(size_t)s3 * F + c]);
#pragma unroll
        for (int v = 0; v < 8; ++v)
            acc[v] += (b2f((ushort)r0[v]) + b2f((ushort)r1[v])) +
                      (b2f((ushort)r2[v]) + b2f((ushort)r3[v]));
    }
    for (; e < end; ++e) {
        int s = adj[e];
        short8 r = *reinterpret_cast<const short8*>(&Yl[(size_t)s * F + c]);
#pragma unroll
        for (int v = 0; v < 8; ++v) acc[v] += b2f((ushort)r[v]);
    }

    const int d = end - start;
    const float inv = 1.0f / (float)(d > 0 ? d : 1);
    short8 sv = *reinterpret_cast<const short8*>(&Yr[(size_t)node * F + c]);
    float4 bv0 = *reinterpret_cast<const float4*>(&bias[c]);
    float4 bv1 = *reinterpret_cast<const float4*>(&bias[c + 4]);
    float bb[8] = {bv0.x, bv0.y, bv0.z, bv0.w, bv1.x, bv1.y, bv1.z, bv1.w};
    short8 o;
#pragma unroll
    for (int v = 0; v < 8; ++v)
        o[v] = (short)f2b(fmaxf(acc[v] * inv + b2f((ushort)sv[v]) + bb[v], 0.f));
    *reinterpret_cast<short8*>(&H[(size_t)node * F + c]) = o;
}

// ---------------- params + Cayley fused ----------------
// Phase 1 (all 256 threads, 8 lanes/node, 32 nodes/block): p = h2 @ Wp^T + bp
// into LDS (pitch 36: lane bank = (4g+l)%32, conflict-free-ish).
// Phase 2 (threads 0..31): per-node Cayley O = (I-A)^{-1}(I+A) -> Out.

__global__ __launch_bounds__(256)
void params_cayley(const ushort* __restrict__ H2, const float* __restrict__ Wp,
                   const float* __restrict__ bp, float* __restrict__ Out, int n) {
    __shared__ float WpS[32 * 132];
    __shared__ float bpS[32];
    __shared__ float Pl[32][36];
    for (int t = threadIdx.x; t < 32 * 132; t += 256) WpS[t] = 0.f;
    if (threadIdx.x < 32) bpS[threadIdx.x] = (threadIdx.x < 28) ? bp[threadIdx.x] : 0.f;
    __syncthreads();
    for (int t = threadIdx.x; t < 28 * 128; t += 256) {
        int r = t >> 7, c = t & 127;
        WpS[r * 132 + c] = Wp[t];
    }
    __syncthreads();

    const int g = threadIdx.x >> 3;
    const int l = threadIdx.x & 7;
    const int node = blockIdx.x * 32 + g;
    if (node < n) {
        short8 h8[16];
        const short8* hp = reinterpret_cast<const short8*>(&H2[(size_t)node * 128]);
#pragma unroll
        for (int q = 0; q < 16; ++q) h8[q] = hp[q];

        float acc0 = bpS[l], acc1 = bpS[l + 8], acc2 = bpS[l + 16], acc3 = bpS[l + 24];
#pragma unroll
        for (int q = 0; q < 32; ++q) {
            float h0 = b2f((ushort)h8[q >> 1][(q & 1) * 4 + 0]);
            float h1 = b2f((ushort)h8[q >> 1][(q & 1) * 4 + 1]);
            float h2 = b2f((ushort)h8[q >> 1][(q & 1) * 4 + 2]);
            float h3 = b2f((ushort)h8[q >> 1][(q & 1) * 4 + 3]);
            float4 w0 = *reinterpret_cast<const float4*>(&WpS[(l +  0) * 132 + 4 * q]);
            float4 w1 = *reinterpret_cast<const float4*>(&WpS[(l +  8) * 132 + 4 * q]);
            float4 w2 = *reinterpret_cast<const float4*>(&WpS[(l + 16) * 132 + 4 * q]);
            float4 w3 = *reinterpret_cast<const float4*>(&WpS[(l + 24) * 132 + 4 * q]);
            acc0 += h0 * w0.x + h1 * w0.y + h2 * w0.z + h3 * w0.w;
            acc1 += h0 * w1.x + h1 * w1.y + h2 * w1.z + h3 * w1.w;
            acc2 += h0 * w2.x + h1 * w2.y + h2 * w2.z + h3 * w2.w;
            acc3 += h0 * w3.x + h1 * w3.y + h2 * w3.z + h3 * w3.w;
        }
        Pl[g][l]      = acc0;
        Pl[g][l + 8]  = acc1;
        Pl[g][l + 16] = acc2;
        Pl[g][l + 24] = acc3;
    }
    __syncthreads();

    const int t = threadIdx.x;
    if (t < 32) {
        int nd = blockIdx.x * 32 + t;
        if (nd < n) {
            float p[28];
#pragma unroll
            for (int j = 0; j < 28; ++j) p[j] = Pl[t][j];

            float M_[8][8], B_[8][8];
#pragma unroll
            for (int r = 0; r < 8; ++r)
#pragma unroll
                for (int c = 0; c < 8; ++c) {
                    M_[r][c] = (r == c) ? 1.f : 0.f;
                    B_[r][c] = (r == c) ? 1.f : 0.f;
                }
            {
                int idx = 0;
#pragma unroll
                for (int r = 0; r < 8; ++r)
#pragma unroll
                    for (int c = r + 1; c < 8; ++c) {
                        float a = p[idx++];
                        M_[r][c] -= a;  M_[c][r] += a;
                        B_[r][c] += a;  B_[c][r] -= a;
                    }
            }
#pragma unroll
            for (int col = 0; col < 8; ++col) {
                float inv = 1.0f / M_[col][col];
#pragma unroll
                for (int c = 0; c < 8; ++c) { M_[col][c] *= inv; B_[col][c] *= inv; }
#pragma unroll
                for (int r = 0; r < 8; ++r) {
                    if (r == col) continue;
                    float f = M_[r][col];
#pragma unroll
                    for (int c = 0; c < 8; ++c) {
                        M_[r][c] -= f * M_[col][c];
                        B_[r][c] -= f * B_[col][c];
                    }
                }
            }
            float* out = &Out[(size_t)nd * 64];
#pragma unroll
            for (int r = 0; r < 8; ++r) {
                float4 o0 = make_float4(B_[r][0], B_[r][1], B_[r][2], B_[r][3]);
                float4 o1 = make_float4(B_[r][4], B_[r][5], B_[r][6], B_[r][7]);
                *reinterpret_cast<float4*>(&out[r * 8 + 0]) = o0;
                *reinterpret_cast<float4*>(&out[r * 8 + 4]) = o1;
            }
        }
    }
}

// ---------------------------------------------------------------------------

extern "C" void kernel_launch(void* const* d_in, const int* in_sizes, int n_in,
                              void* d_out, int out_size, void* d_ws, size_t ws_size,
                              hipStream_t stream) {
    const float* x   = (const float*)d_in[0];
    const int*   ei  = (const int*)d_in[1];
    const float* W1l = (const float*)d_in[2];
    const float* b1  = (const float*)d_in[3];
    const float* W1r = (const float*)d_in[4];
    const float* W2l = (const float*)d_in[5];
    const float* b2  = (const float*)d_in[6];
    const float* W2r = (const float*)d_in[7];
    const float* Wp  = (const float*)d_in[8];
    const float* bp  = (const float*)d_in[9];
    float* out = (float*)d_out;

    const int IN_DIM = 512;
    const int N = in_sizes[0] / IN_DIM;   // 50000
    const int E = in_sizes[1] / 2;        // 800000

    char* ws = (char*)d_ws;
    size_t off = 0;
    int* deg      = (int*)(ws + off); off = WS_ALIGN(off + (size_t)N * 4);
    int* rowptr   = (int*)(ws + off); off = WS_ALIGN(off + (size_t)(N + 1) * 4);
    int* cursor   = (int*)(ws + off); off = WS_ALIGN(off + (size_t)N * 4);
    int* bsum     = (int*)(ws + off); off = WS_ALIGN(off + (size_t)256 * 4);
    int* adj      = (int*)(ws + off); off = WS_ALIGN(off + (size_t)E * 4);
    ushort* Yl    = (ushort*)(ws + off); off = WS_ALIGN(off + (size_t)N * 256 * 2);
    ushort* Yr    = (ushort*)(ws + off); off = WS_ALIGN(off + (size_t)N * 256 * 2);
    ushort* h1    = (ushort*)(ws + off); off = WS_ALIGN(off + (size_t)N * 256 * 2);
    ushort* zl    = (ushort*)(ws + off); off = WS_ALIGN(off + (size_t)N * 128 * 2);
    ushort* zr    = (ushort*)(ws + off); off = WS_ALIGN(off + (size_t)N * 128 * 2);
    ushort* Wc1   = (ushort*)(ws + off); off = WS_ALIGN(off + (size_t)512 * 512 * 2);
    ushort* Wc2   = (ushort*)(ws + off); off = WS_ALIGN(off + (size_t)256 * 256 * 2);

    const int* src = ei;
    const int* dst = ei + E;

    hipMemsetAsync(deg, 0, (size_t)N * 4, stream);

    const int eb = (E + 255) / 256;       // 3125 (scatter grid)
    const int wb = ((512 * 512 + 256 * 256) / 8 + 255) / 256;   // 160
    const int nb = (N + 1023) / 1024;     // <= 256
    const int gm = (N + 127) / 128;       // 391
    const int hb = (E + 1023) / 1024;     // hist y-rows (2 blocks x 512 thr)

    // weight concat+cast (must precede GEMM1)
    prep_kernel<<<wb, 256, 0, stream>>>(W1l, W1r, W2l, W2r, Wc1, Wc2);

    // layer 1 GEMM + fused degree histogram (independent work, one dispatch)
    gemm_wide<true, 256, true><<<dim3(2, gm + hb), 512, 0, stream>>>(
        x, (const ushort*)nullptr, Wc1, Yl, Yr, N, 512, 256, gm, dst, deg, E);

    // CSR build (hist already done above)
    scan_phase1<<<nb, 256, 0, stream>>>(deg, bsum, N);
    scan_phase2<<<1, 256, 0, stream>>>(bsum, rowptr, nb, N);
    scan_phase3<<<nb, 256, 0, stream>>>(deg, bsum, rowptr, cursor, N);
    scatter_kernel<<<eb, 256, 0, stream>>>(src, dst, rowptr, cursor, adj, E);

    // h1 = relu(mean + self + b1)  [N,256] bf16 (32 lanes/node, 16B loads)
    aggregate_bf16<32><<<(N + 7) / 8, 256, 0, stream>>>(Yl, Yr, b1, rowptr, adj, h1, N);

    // layer 2: [zl|zr] = h1 @ Wc2^T  (BN=128 -> 782 blocks)
    gemm_wide<false, 128, false><<<dim3(2, gm), 512, 0, stream>>>(
        (const float*)nullptr, h1, Wc2, zl, zr, N, 256, 128, gm,
        (const int*)nullptr, (int*)nullptr, 0);

    // h2  [N,128] bf16 (reuse Yl; 16 lanes/node)
    ushort* h2 = Yl;
    aggregate_bf16<16><<<(N + 15) / 16, 256, 0, stream>>>(zl, zr, b2, rowptr, adj, h2, N);

    // params + Cayley fused -> out [N,8,8] fp32
    params_cayley<<<(N + 31) / 32, 256, 0, stream>>>(h2, Wp, bp, out, N);
}

// Round 15
// 261.596 us; speedup vs baseline: 2.1580x; 2.1580x over previous
//
#include <hip/hip_runtime.h>
#include <hip/hip_bf16.h>

// ---------------------------------------------------------------------------
// InductiveBundleMapLearner: 2x SAGEConv (mean) -> linear -> Cayley map
// R13 core with (512,4) launch bounds (R14's (512,6) spilled acc -> scratch).
// Kept from R14 (verified correct, not implicated in the spill):
//   hist fused into GEMM1 dispatch, BN-templated GEMM2 (BN=128, 782 blocks),
//   params+cayley fused via LDS.
// ---------------------------------------------------------------------------

#define WS_ALIGN(x) (((x) + 255) & ~size_t(255))

typedef __attribute__((ext_vector_type(8))) short short8;
typedef __attribute__((ext_vector_type(4))) float floatx4;

static __device__ __forceinline__ ushort f2b(float f) {
    unsigned u = __builtin_bit_cast(unsigned, f);
    u = (u + 0x7fffu + ((u >> 16) & 1u)) >> 16;   // RNE, finite inputs
    return (ushort)u;
}
static __device__ __forceinline__ float b2f(ushort h) {
    unsigned u = ((unsigned)h) << 16;
    return __builtin_bit_cast(float, u);
}
static __device__ __forceinline__ unsigned pk2(float a, float b) {
    return (unsigned)f2b(a) | ((unsigned)f2b(b) << 16);
}

// ---------------- prep: build_wcat only (hist lives in GEMM1) ----------------

__global__ __launch_bounds__(256)
void prep_kernel(const float* __restrict__ W1l, const float* __restrict__ W1r,
                 const float* __restrict__ W2l, const float* __restrict__ W2r,
                 ushort* __restrict__ Wc1, ushort* __restrict__ Wc2) {
    int idx = blockIdx.x * blockDim.x + threadIdx.x;
    const int n1 = (512 * 512) / 8;
    const int n2 = (256 * 256) / 8;
    const float* src;
    ushort* dstp;
    if (idx < n1) {
        int e = idx * 8;
        int row = e >> 9, col = e & 511;
        src = (row < 256) ? &W1l[row * 512 + col] : &W1r[(row - 256) * 512 + col];
        dstp = &Wc1[e];
    } else if (idx < n1 + n2) {
        int e = (idx - n1) * 8;
        int row = e >> 8, col = e & 255;
        src = (row < 128) ? &W2l[row * 256 + col] : &W2r[(row - 128) * 256 + col];
        dstp = &Wc2[e];
    } else {
        return;
    }
    const float4* s4 = reinterpret_cast<const float4*>(src);
    float4 v0 = s4[0], v1 = s4[1];
    short8 o;
    o[0] = (short)f2b(v0.x); o[1] = (short)f2b(v0.y);
    o[2] = (short)f2b(v0.z); o[3] = (short)f2b(v0.w);
    o[4] = (short)f2b(v1.x); o[5] = (short)f2b(v1.y);
    o[6] = (short)f2b(v1.z); o[7] = (short)f2b(v1.w);
    *reinterpret_cast<short8*>(dstp) = o;
}

// ---------------- scan (3-phase) ----------------

__global__ __launch_bounds__(256)
void scan_phase1(const int* __restrict__ deg, int* __restrict__ bsum, int n) {
    __shared__ int red[256];
    const int t = threadIdx.x;
    const int i = blockIdx.x * 1024 + t * 4;
    int s = 0;
    if (i + 4 <= n) {
        int4 v = *reinterpret_cast<const int4*>(&deg[i]);
        s = v.x + v.y + v.z + v.w;
    } else {
        for (int k = i; k < n; ++k) s += deg[k];
    }
    red[t] = s;
    __syncthreads();
#pragma unroll
    for (int off = 128; off > 0; off >>= 1) {
        if (t < off) red[t] += red[t + off];
        __syncthreads();
    }
    if (t == 0) bsum[blockIdx.x] = red[0];
}

__global__ __launch_bounds__(256)
void scan_phase2(int* __restrict__ bsum, int* __restrict__ rowptr, int nb, int n) {
    __shared__ int sh[256];
    const int t = threadIdx.x;
    int orig = (t < nb) ? bsum[t] : 0;
    sh[t] = orig;
    __syncthreads();
#pragma unroll
    for (int off = 1; off < 256; off <<= 1) {
        int v = (t >= off) ? sh[t - off] : 0;
        __syncthreads();
        sh[t] += v;
        __syncthreads();
    }
    if (t < nb) bsum[t] = sh[t] - orig;          // exclusive block offsets
    if (t == 255) rowptr[n] = sh[255];           // total
}

// phase 3 also zero-fills cursor
__global__ __launch_bounds__(256)
void scan_phase3(const int* __restrict__ deg, const int* __restrict__ bsum,
                 int* __restrict__ rowptr, int* __restrict__ cursor, int n) {
    __shared__ int red[256];
    const int t = threadIdx.x;
    const int i = blockIdx.x * 1024 + t * 4;
    int v0 = 0, v1 = 0, v2 = 0, v3 = 0;
    if (i + 4 <= n) {
        int4 v = *reinterpret_cast<const int4*>(&deg[i]);
        v0 = v.x; v1 = v.y; v2 = v.z; v3 = v.w;
    } else {
        if (i     < n) v0 = deg[i];
        if (i + 1 < n) v1 = deg[i + 1];
        if (i + 2 < n) v2 = deg[i + 2];
        if (i + 3 < n) v3 = deg[i + 3];
    }
    int s = v0 + v1 + v2 + v3;
    red[t] = s;
    __syncthreads();
#pragma unroll
    for (int off = 1; off < 256; off <<= 1) {
        int u = (t >= off) ? red[t - off] : 0;
        __syncthreads();
        red[t] += u;
        __syncthreads();
    }
    int pre = bsum[blockIdx.x] + red[t] - s;
    if (i + 4 <= n) {
        int4 o;
        o.x = pre; o.y = pre + v0; o.z = pre + v0 + v1; o.w = pre + v0 + v1 + v2;
        *reinterpret_cast<int4*>(&rowptr[i]) = o;
        *reinterpret_cast<int4*>(&cursor[i]) = make_int4(0, 0, 0, 0);
    } else {
        if (i     < n) { rowptr[i]     = pre;                cursor[i]     = 0; }
        if (i + 1 < n) { rowptr[i + 1] = pre + v0;           cursor[i + 1] = 0; }
        if (i + 2 < n) { rowptr[i + 2] = pre + v0 + v1;      cursor[i + 2] = 0; }
        if (i + 3 < n) { rowptr[i + 3] = pre + v0 + v1 + v2; cursor[i + 3] = 0; }
    }
}

__global__ void scatter_kernel(const int* __restrict__ src, const int* __restrict__ dst,
                               const int* __restrict__ rowptr, int* __restrict__ cursor,
                               int* __restrict__ adj, int E) {
    int e = blockIdx.x * blockDim.x + threadIdx.x;
    if (e < E) {
        int d = dst[e];
        int p = atomicAdd(&cursor[d], 1);
        adj[rowptr[d] + p] = src[e];
    }
}

// ---------------- bf16 MFMA GEMM: [Cl|Cr] = A @ B^T ----------------
// 128xBN tile, BK=64, 512 threads = 8 waves (2M x 4N; each 64 x BN/4).
// B staged via global_load_lds (pre-swizzled src, linear dest).
// A: CASTA ? pipelined fp32 reg-load -> bf16 pack -> swizzled ds_write
//          : global_load_lds like B.
// HIST: blocks with blockIdx.y >= gmy do the degree histogram instead.
// LDS granule (r, g) lives at byte r*128 + ((g*16) ^ ((r&7)<<4)).
// NOTE: launch bounds (512,4) -- (512,6) caps VGPR at 85 and SPILLS acc
// to scratch (R14: VGPR=40, WRITE_SIZE 843MB, 5.8x slowdown).

template <bool CASTA, int BN, bool HIST>
__global__ __launch_bounds__(512, 4)
void gemm_wide(const float* __restrict__ Af, const ushort* __restrict__ Ab,
               const ushort* __restrict__ B,
               ushort* __restrict__ Cl, ushort* __restrict__ Cr,
               int M, int K, int S, int gmy,
               const int* __restrict__ hdst, int* __restrict__ hdeg, int hE) {
    if (HIST) {
        if (blockIdx.y >= gmy) {
            int e = ((blockIdx.y - gmy) * gridDim.x + blockIdx.x) * 512 + threadIdx.x;
            if (e < hE) atomicAdd(&hdeg[hdst[e]], 1);
            return;
        }
    }
    constexpr int WN = BN / 4;     // cols per wave
    constexpr int NI = BN / 64;    // 16-col groups per wave (acc N dim)
    __shared__ ushort As[128 * 64];    // 16 KB
    __shared__ ushort Bs[BN * 64];     // BN/8 KB
    const int tid  = threadIdx.x;
    const int wave = tid >> 6;
    const int lane = tid & 63;
    const int row0 = blockIdx.y * 128;
    const int col0 = blockIdx.x * BN;
    const int wm = (wave & 1) * 64;
    const int wn = (wave >> 1) * WN;

    floatx4 acc[4][NI];
#pragma unroll
    for (int i = 0; i < 4; ++i)
#pragma unroll
        for (int j = 0; j < NI; ++j)
            acc[i][j] = (floatx4){0.f, 0.f, 0.f, 0.f};

    const int rsub = lane >> 3;                        // row within 8-row chunk
    const int ksw  = ((lane & 7) * 16) ^ (rsub << 4);  // pre-swizzled byte-in-row

    // CASTA addressing: thread owns row r = tid>>2, quarter qt = tid&3
    const int ar = tid >> 2;
    const int aq = tid & 3;
    int agrow = row0 + ar; if (agrow >= M) agrow = M - 1;
    const float* arow_base = CASTA ? (Af + (size_t)agrow * K + aq * 16) : nullptr;
    char* alds = (char*)As + ar * 128;
    const int arx = (ar & 7) << 4;

    float4 va0, va1, va2, va3;
    if constexpr (CASTA) {
        const float* s0 = arow_base;                   // k0 = 0 prologue
        va0 = *reinterpret_cast<const float4*>(s0 + 0);
        va1 = *reinterpret_cast<const float4*>(s0 + 4);
        va2 = *reinterpret_cast<const float4*>(s0 + 8);
        va3 = *reinterpret_cast<const float4*>(s0 + 12);
    }

    for (int k0 = 0; k0 < K; k0 += 64) {
        // ---- issue B DMA first (longest queue): BN/8 chunks, NI per wave ----
#pragma unroll
        for (int i = 0; i < NI; ++i) {
            int chunk = wave * NI + i;
            int r = chunk * 8 + rsub;
            int gcol = col0 + r;
            const char* src = (const char*)(B + (size_t)gcol * K + k0) + ksw;
            __builtin_amdgcn_global_load_lds(
                (const __attribute__((address_space(1))) unsigned int*)src,
                (__attribute__((address_space(3))) unsigned int*)(&Bs[chunk * 512]),
                16, 0, 0);
        }
        // ---- stage A ----
        if constexpr (CASTA) {
            uint4 o0 = make_uint4(pk2(va0.x, va0.y), pk2(va0.z, va0.w),
                                  pk2(va1.x, va1.y), pk2(va1.z, va1.w));
            uint4 o1 = make_uint4(pk2(va2.x, va2.y), pk2(va2.z, va2.w),
                                  pk2(va3.x, va3.y), pk2(va3.z, va3.w));
            int g0 = aq * 2;
            *reinterpret_cast<uint4*>(alds + ((g0 * 16) ^ arx))       = o0;
            *reinterpret_cast<uint4*>(alds + (((g0 + 1) * 16) ^ arx)) = o1;
            if (k0 + 64 < K) {
                const float* s1 = arow_base + k0 + 64;
                va0 = *reinterpret_cast<const float4*>(s1 + 0);
                va1 = *reinterpret_cast<const float4*>(s1 + 4);
                va2 = *reinterpret_cast<const float4*>(s1 + 8);
                va3 = *reinterpret_cast<const float4*>(s1 + 12);
            }
        } else {
            // 16 chunks, 2 per wave
#pragma unroll
            for (int i = 0; i < 2; ++i) {
                int chunk = wave * 2 + i;
                int r = chunk * 8 + rsub;
                int grow = row0 + r;
                if (grow >= M) grow = M - 1;           // clamp (stores guarded)
                const char* src = (const char*)(Ab + (size_t)grow * K + k0) + ksw;
                __builtin_amdgcn_global_load_lds(
                    (const __attribute__((address_space(1))) unsigned int*)src,
                    (__attribute__((address_space(3))) unsigned int*)(&As[chunk * 512]),
                    16, 0, 0);
            }
        }
        __syncthreads();

#pragma unroll
        for (int kk = 0; kk < 2; ++kk) {
            short8 af[4], bf[NI];
            const int kb = (kk * 64 + ((lane >> 4) << 4)) ^ ((lane & 7) << 4);
#pragma unroll
            for (int im = 0; im < 4; ++im) {
                int r = wm + im * 16 + (lane & 15);
                af[im] = *reinterpret_cast<const short8*>((const char*)As + r * 128 + kb);
            }
#pragma unroll
            for (int in = 0; in < NI; ++in) {
                int r = wn + in * 16 + (lane & 15);
                bf[in] = *reinterpret_cast<const short8*>((const char*)Bs + r * 128 + kb);
            }
#pragma unroll
            for (int im = 0; im < 4; ++im)
#pragma unroll
                for (int in = 0; in < NI; ++in)
                    acc[im][in] = __builtin_amdgcn_mfma_f32_16x16x32_bf16(
                        af[im], bf[in], acc[im][in], 0, 0, 0);
        }
        __syncthreads();
    }

    // epilogue: C/D layout col=lane&15, row=(lane>>4)*4+reg
#pragma unroll
    for (int im = 0; im < 4; ++im) {
#pragma unroll
        for (int reg = 0; reg < 4; ++reg) {
            int r = row0 + wm + im * 16 + ((lane >> 4) << 2) + reg;
            if (r < M) {
#pragma unroll
                for (int in = 0; in < NI; ++in) {
                    int g = col0 + wn + in * 16 + (lane & 15);
                    if (g < S) Cl[(size_t)r * S + g] = f2b(acc[im][in][reg]);
                    else       Cr[(size_t)r * S + (g - S)] = f2b(acc[im][in][reg]);
                }
            }
        }
    }
}

// ---------------- aggregation: h = relu(mean_l + self_r + b), bf16 ----------------
// Yl/Yr = [N, F] split buffers. LPN lanes/node, 8 ch/lane (16B short8 loads).

template <int LPN>
__global__ __launch_bounds__(256)
void aggregate_bf16(const ushort* __restrict__ Yl, const ushort* __restrict__ Yr,
                    const float* __restrict__ bias,
                    const int* __restrict__ rowptr, const int* __restrict__ adj,
                    ushort* __restrict__ H, int n) {
    constexpr int F = LPN * 8;
    const int grp = threadIdx.x / LPN;
    const int sub = threadIdx.x % LPN;
    const int node = blockIdx.x * (256 / LPN) + grp;
    if (node >= n) return;
    const int c = sub * 8;
    const int start = rowptr[node], end = rowptr[node + 1];

    float acc[8];
#pragma unroll
    for (int v = 0; v < 8; ++v) acc[v] = 0.f;

    int e = start;
    for (; e + 4 <= end; e += 4) {
        int s0 = adj[e + 0], s1 = adj[e + 1], s2 = adj[e + 2], s3 = adj[e + 3];
        short8 r0 = *reinterpret_cast<const short8*>(&Yl[(size_t)s0 * F + c]);
        short8 r1 = *reinterpret_cast<const short8*>(&Yl[(size_t)s1 * F + c]);
        short8 r2 = *reinterpret_cast<const short8*>(&Yl[(size_t)s2 * F + c]);
        short8 r3 = *reinterpret_cast<const short8*>(&Yl[(size_t)s3 * F + c]);
#pragma unroll
        for (int v = 0; v < 8; ++v)
            acc[v] += (b2f((ushort)r0[v]) + b2f((ushort)r1[v])) +
                      (b2f((ushort)r2[v]) + b2f((ushort)r3[v]));
    }
    for (; e < end; ++e) {
        int s = adj[e];
        short8 r = *reinterpret_cast<const short8*>(&Yl[(size_t)s * F + c]);
#pragma unroll
        for (int v = 0; v < 8; ++v) acc[v] += b2f((ushort)r[v]);
    }

    const int d = end - start;
    const float inv = 1.0f / (float)(d > 0 ? d : 1);
    short8 sv = *reinterpret_cast<const short8*>(&Yr[(size_t)node * F + c]);
    float4 bv0 = *reinterpret_cast<const float4*>(&bias[c]);
    float4 bv1 = *reinterpret_cast<const float4*>(&bias[c + 4]);
    float bb[8] = {bv0.x, bv0.y, bv0.z, bv0.w, bv1.x, bv1.y, bv1.z, bv1.w};
    short8 o;
#pragma unroll
    for (int v = 0; v < 8; ++v)
        o[v] = (short)f2b(fmaxf(acc[v] * inv + b2f((ushort)sv[v]) + bb[v], 0.f));
    *reinterpret_cast<short8*>(&H[(size_t)node * F + c]) = o;
}

// ---------------- params + Cayley fused ----------------
// Phase 1 (256 threads, 8 lanes/node, 32 nodes/block): p = h2 @ Wp^T + bp
// into LDS (pitch-132 WpS -> conflict-free float4 reads). Phase 2 (threads
// 0..31): per-node Cayley O = (I-A)^{-1}(I+A) -> Out. Verified in R14.

__global__ __launch_bounds__(256)
void params_cayley(const ushort* __restrict__ H2, const float* __restrict__ Wp,
                   const float* __restrict__ bp, float* __restrict__ Out, int n) {
    __shared__ float WpS[32 * 132];
    __shared__ float bpS[32];
    __shared__ float Pl[32][36];
    for (int t = threadIdx.x; t < 32 * 132; t += 256) WpS[t] = 0.f;
    if (threadIdx.x < 32) bpS[threadIdx.x] = (threadIdx.x < 28) ? bp[threadIdx.x] : 0.f;
    __syncthreads();
    for (int t = threadIdx.x; t < 28 * 128; t += 256) {
        int r = t >> 7, c = t & 127;
        WpS[r * 132 + c] = Wp[t];
    }
    __syncthreads();

    const int g = threadIdx.x >> 3;
    const int l = threadIdx.x & 7;
    const int node = blockIdx.x * 32 + g;
    if (node < n) {
        short8 h8[16];
        const short8* hp = reinterpret_cast<const short8*>(&H2[(size_t)node * 128]);
#pragma unroll
        for (int q = 0; q < 16; ++q) h8[q] = hp[q];

        float acc0 = bpS[l], acc1 = bpS[l + 8], acc2 = bpS[l + 16], acc3 = bpS[l + 24];
#pragma unroll
        for (int q = 0; q < 32; ++q) {
            float h0 = b2f((ushort)h8[q >> 1][(q & 1) * 4 + 0]);
            float h1 = b2f((ushort)h8[q >> 1][(q & 1) * 4 + 1]);
            float h2 = b2f((ushort)h8[q >> 1][(q & 1) * 4 + 2]);
            float h3 = b2f((ushort)h8[q >> 1][(q & 1) * 4 + 3]);
            float4 w0 = *reinterpret_cast<const float4*>(&WpS[(l +  0) * 132 + 4 * q]);
            float4 w1 = *reinterpret_cast<const float4*>(&WpS[(l +  8) * 132 + 4 * q]);
            float4 w2 = *reinterpret_cast<const float4*>(&WpS[(l + 16) * 132 + 4 * q]);
            float4 w3 = *reinterpret_cast<const float4*>(&WpS[(l + 24) * 132 + 4 * q]);
            acc0 += h0 * w0.x + h1 * w0.y + h2 * w0.z + h3 * w0.w;
            acc1 += h0 * w1.x + h1 * w1.y + h2 * w1.z + h3 * w1.w;
            acc2 += h0 * w2.x + h1 * w2.y + h2 * w2.z + h3 * w2.w;
            acc3 += h0 * w3.x + h1 * w3.y + h2 * w3.z + h3 * w3.w;
        }
        Pl[g][l]      = acc0;
        Pl[g][l + 8]  = acc1;
        Pl[g][l + 16] = acc2;
        Pl[g][l + 24] = acc3;
    }
    __syncthreads();

    const int t = threadIdx.x;
    if (t < 32) {
        int nd = blockIdx.x * 32 + t;
        if (nd < n) {
            float p[28];
#pragma unroll
            for (int j = 0; j < 28; ++j) p[j] = Pl[t][j];

            float M_[8][8], B_[8][8];
#pragma unroll
            for (int r = 0; r < 8; ++r)
#pragma unroll
                for (int c = 0; c < 8; ++c) {
                    M_[r][c] = (r == c) ? 1.f : 0.f;
                    B_[r][c] = (r == c) ? 1.f : 0.f;
                }
            {
                int idx = 0;
#pragma unroll
                for (int r = 0; r < 8; ++r)
#pragma unroll
                    for (int c = r + 1; c < 8; ++c) {
                        float a = p[idx++];
                        M_[r][c] -= a;  M_[c][r] += a;
                        B_[r][c] += a;  B_[c][r] -= a;
                    }
            }
#pragma unroll
            for (int col = 0; col < 8; ++col) {
                float inv = 1.0f / M_[col][col];
#pragma unroll
                for (int c = 0; c < 8; ++c) { M_[col][c] *= inv; B_[col][c] *= inv; }
#pragma unroll
                for (int r = 0; r < 8; ++r) {
                    if (r == col) continue;
                    float f = M_[r][col];
#pragma unroll
                    for (int c = 0; c < 8; ++c) {
                        M_[r][c] -= f * M_[col][c];
                        B_[r][c] -= f * B_[col][c];
                    }
                }
            }
            float* out = &Out[(size_t)nd * 64];
#pragma unroll
            for (int r = 0; r < 8; ++r) {
                float4 o0 = make_float4(B_[r][0], B_[r][1], B_[r][2], B_[r][3]);
                float4 o1 = make_float4(B_[r][4], B_[r][5], B_[r][6], B_[r][7]);
                *reinterpret_cast<float4*>(&out[r * 8 + 0]) = o0;
                *reinterpret_cast<float4*>(&out[r * 8 + 4]) = o1;
            }
        }
    }
}

// ---------------------------------------------------------------------------

extern "C" void kernel_launch(void* const* d_in, const int* in_sizes, int n_in,
                              void* d_out, int out_size, void* d_ws, size_t ws_size,
                              hipStream_t stream) {
    const float* x   = (const float*)d_in[0];
    const int*   ei  = (const int*)d_in[1];
    const float* W1l = (const float*)d_in[2];
    const float* b1  = (const float*)d_in[3];
    const float* W1r = (const float*)d_in[4];
    const float* W2l = (const float*)d_in[5];
    const float* b2  = (const float*)d_in[6];
    const float* W2r = (const float*)d_in[7];
    const float* Wp  = (const float*)d_in[8];
    const float* bp  = (const float*)d_in[9];
    float* out = (float*)d_out;

    const int IN_DIM = 512;
    const int N = in_sizes[0] / IN_DIM;   // 50000
    const int E = in_sizes[1] / 2;        // 800000

    char* ws = (char*)d_ws;
    size_t off = 0;
    int* deg      = (int*)(ws + off); off = WS_ALIGN(off + (size_t)N * 4);
    int* rowptr   = (int*)(ws + off); off = WS_ALIGN(off + (size_t)(N + 1) * 4);
    int* cursor   = (int*)(ws + off); off = WS_ALIGN(off + (size_t)N * 4);
    int* bsum     = (int*)(ws + off); off = WS_ALIGN(off + (size_t)256 * 4);
    int* adj      = (int*)(ws + off); off = WS_ALIGN(off + (size_t)E * 4);
    ushort* Yl    = (ushort*)(ws + off); off = WS_ALIGN(off + (size_t)N * 256 * 2);
    ushort* Yr    = (ushort*)(ws + off); off = WS_ALIGN(off + (size_t)N * 256 * 2);
    ushort* h1    = (ushort*)(ws + off); off = WS_ALIGN(off + (size_t)N * 256 * 2);
    ushort* zl    = (ushort*)(ws + off); off = WS_ALIGN(off + (size_t)N * 128 * 2);
    ushort* zr    = (ushort*)(ws + off); off = WS_ALIGN(off + (size_t)N * 128 * 2);
    ushort* Wc1   = (ushort*)(ws + off); off = WS_ALIGN(off + (size_t)512 * 512 * 2);
    ushort* Wc2   = (ushort*)(ws + off); off = WS_ALIGN(off + (size_t)256 * 256 * 2);

    const int* src = ei;
    const int* dst = ei + E;

    hipMemsetAsync(deg, 0, (size_t)N * 4, stream);

    const int eb = (E + 255) / 256;       // 3125 (scatter grid)
    const int wb = ((512 * 512 + 256 * 256) / 8 + 255) / 256;   // 160
    const int nb = (N + 1023) / 1024;     // <= 256
    const int gm = (N + 127) / 128;       // 391
    const int hb = (E + 1023) / 1024;     // hist y-rows (2 blocks x 512 thr)

    // weight concat+cast (must precede GEMM1)
    prep_kernel<<<wb, 256, 0, stream>>>(W1l, W1r, W2l, W2r, Wc1, Wc2);

    // layer 1 GEMM + fused degree histogram (independent work, one dispatch)
    gemm_wide<true, 256, true><<<dim3(2, gm + hb), 512, 0, stream>>>(
        x, (const ushort*)nullptr, Wc1, Yl, Yr, N, 512, 256, gm, dst, deg, E);

    // CSR build
    scan_phase1<<<nb, 256, 0, stream>>>(deg, bsum, N);
    scan_phase2<<<1, 256, 0, stream>>>(bsum, rowptr, nb, N);
    scan_phase3<<<nb, 256, 0, stream>>>(deg, bsum, rowptr, cursor, N);
    scatter_kernel<<<eb, 256, 0, stream>>>(src, dst, rowptr, cursor, adj, E);

    // h1 = relu(mean + self + b1)  [N,256] bf16 (32 lanes/node, 16B loads)
    aggregate_bf16<32><<<(N + 7) / 8, 256, 0, stream>>>(Yl, Yr, b1, rowptr, adj, h1, N);

    // layer 2: [zl|zr] = h1 @ Wc2^T  (BN=128 -> 782 blocks)
    gemm_wide<false, 128, false><<<dim3(2, gm), 512, 0, stream>>>(
        (const float*)nullptr, h1, Wc2, zl, zr, N, 256, 128, gm,
        (const int*)nullptr, (int*)nullptr, 0);

    // h2  [N,128] bf16 (reuse Yl; 16 lanes/node)
    ushort* h2 = Yl;
    aggregate_bf16<16><<<(N + 15) / 16, 256, 0, stream>>>(zl, zr, b2, rowptr, adj, h2, N);

    // params + Cayley fused -> out [N,8,8] fp32
    params_cayley<<<(N + 31) / 32, 256, 0, stream>>>(h2, Wp, bp, out, N);
}